// Round 17
// baseline (574.805 us; speedup 1.0000x reference)
//
#include <hip/hip_runtime.h>
#include <hip/hip_bf16.h>

// Problem constants
#define N0 150000
#define N1 75000
#define EE 200000
#define NAL 50000
#define NSEG (N0 + N1)
#define NSEG2 (2 * NSEG)
#define TOTE (4 * EE)

typedef unsigned short u16;
using s16x8 = __attribute__((ext_vector_type(8))) short;
using f32x4 = __attribute__((ext_vector_type(4))) float;
using u16x4 = __attribute__((ext_vector_type(4))) unsigned short;
using u16x8 = __attribute__((ext_vector_type(8))) unsigned short;

__device__ __forceinline__ u16 f2b(float f) {
  unsigned int b = __float_as_uint(f);
  b += 0x7FFFu + ((b >> 16) & 1u);   // RNE
  return (u16)(b >> 16);
}
__device__ __forceinline__ float b2f(u16 u) {
  return __uint_as_float(((unsigned int)u) << 16);
}

// ---------------- diagnostic sentinel (f32 out)
__global__ void sentinel_k(float* out, float val) {
  if (threadIdx.x == 0 && blockIdx.x == 0) out[0] = val;
}

// ---------------- pack weights bf16: BP[i][slot][o][k]
// slot order: 0:Ws_j0 1:Wt_j0 2:Wt_j2 3:Ws_j1 4:Ws_j2 5:Ws_j3 6:Wt_j1 7:Wt_j3
__global__ __launch_bounds__(256) void prep_w(const float* __restrict__ Ws,
                                              const float* __restrict__ Wt,
                                              u16* __restrict__ BP) {
  int idx = blockIdx.x * 256 + threadIdx.x;   // grid covers 3*8*16384 exactly
  int mk = idx & 16383;
  int slot = (idx >> 14) & 7;
  int i = idx >> 17;
  const int ssel[8] = {1, 0, 0, 1, 1, 1, 0, 0};
  const int sj[8]   = {0, 0, 2, 1, 2, 3, 1, 3};
  const float* W = ssel[slot] ? Ws : Wt;
  BP[idx] = f2b(W[(size_t)(i * 4 + sj[slot]) * 16384 + mk]);
}

// ---------------- embedding gather -> bf16 xs
__global__ __launch_bounds__(256) void embed_k(const int* __restrict__ ids,
                                               const float* __restrict__ tab,
                                               u16* __restrict__ X, int N, unsigned vocab) {
  int idx = blockIdx.x * 256 + threadIdx.x;
  int v = idx >> 4;
  if (v >= N) return;
  int q = (idx & 15) << 3;
  unsigned id = (unsigned)ids[v];
  if (id >= vocab) id = 0;          // defensive
  const float* src = tab + (size_t)id * 128 + q;
  f32x4 x0 = *(const f32x4*)src;
  f32x4 x1 = *(const f32x4*)(src + 4);
  u16x8 o;
#pragma unroll
  for (int k = 0; k < 4; ++k) { o[k] = f2b(x0[k]); o[4 + k] = f2b(x1[k]); }
  *(u16x8*)(X + (size_t)v * 128 + q) = o;
}

// ---------------- merged CSR build, split by si: seg2 = 2*(dst or N0+dst) + (j>>1)
__global__ __launch_bounds__(256) void count_all(const int* __restrict__ e0,
                                                 const int* __restrict__ e1,
                                                 const int* __restrict__ e2,
                                                 const int* __restrict__ e3,
                                                 int* __restrict__ cnt) {
  int i = blockIdx.x * 256 + threadIdx.x;
  if (i >= TOTE) return;
  int j = i / EE, r = i - j * EE;
  const int* es = (j == 0) ? e0 : (j == 1) ? e1 : (j == 2) ? e2 : e3;
  int dst = es[EE + r];
  int seg = (j & 1) ? N0 + dst : dst;
  atomicAdd(cnt + seg * 2 + (j >> 1), 1);
}

// 512-thread scan blocks so NSEG2=450000 -> 879 partials (<=1024)
__global__ __launch_bounds__(512) void scan1_k(const int* __restrict__ cnt,
                                               int* __restrict__ off,
                                               int* __restrict__ part, int N) {
  __shared__ int sh[512];
  int t = threadIdx.x, i = blockIdx.x * 512 + t;
  int v = (i < N) ? cnt[i] : 0;
  sh[t] = v; __syncthreads();
  for (int s = 1; s < 512; s <<= 1) {
    int x = (t >= s) ? sh[t - s] : 0; __syncthreads();
    sh[t] += x; __syncthreads();
  }
  if (i < N) off[i] = sh[t] - v;                 // exclusive within block
  if (t == 511) part[blockIdx.x] = sh[511];      // block total
}

__global__ __launch_bounds__(1024) void scan2_k(int* __restrict__ part, int n) {
  __shared__ int sh[1024];
  int t = threadIdx.x;
  int v = (t < n) ? part[t] : 0;
  sh[t] = v; __syncthreads();
  for (int s = 1; s < 1024; s <<= 1) {
    int x = (t >= s) ? sh[t - s] : 0; __syncthreads();
    sh[t] += x; __syncthreads();
  }
  if (t < n) part[t] = sh[t] - v;                // exclusive
}

__global__ __launch_bounds__(256) void scan3_k(int* __restrict__ off,
                                               const int* __restrict__ part, int N, int tot) {
  int i = blockIdx.x * 256 + threadIdx.x;
  if (i < N) off[i] += part[i >> 9];
  if (i == 0) off[N] = tot;
}

// einfo[pos] = src | (self << 31); si is implied by subsegment range
__global__ __launch_bounds__(256) void fill_all(const int* __restrict__ e0,
                                                const int* __restrict__ e1,
                                                const int* __restrict__ e2,
                                                const int* __restrict__ e3,
                                                const int* __restrict__ off,
                                                int* __restrict__ cur,
                                                int* __restrict__ einfo) {
  int i = blockIdx.x * 256 + threadIdx.x;
  if (i >= TOTE) return;
  int j = i / EE, r = i - j * EE;
  const int* es = (j == 0) ? e0 : (j == 1) ? e1 : (j == 2) ? e2 : e3;
  int src = es[r], dst = es[EE + r];
  int seg2 = ((j & 1) ? N0 + dst : dst) * 2 + (j >> 1);
  int pos = off[seg2] + atomicAdd(cur + seg2, 1);
  einfo[pos] = src | ((src == dst) ? (int)0x80000000 : 0);
}

// ---------------- dual-staged multi-weight MFMA GEMM, half-B staging (r14),
// with SWAPPED MFMA operands: D^T fragment -> each thread holds 4 consecutive
// output cols of one node -> u16x4 8B stores (4x fewer store instrs, same bytes,
// bit-identical math).
__global__ __launch_bounds__(256, 5) void gemm_multi(const u16* __restrict__ A, int M,
                                                     const u16* __restrict__ W, int nw,
                                                     u16* __restrict__ C0,
                                                     u16* __restrict__ C1,
                                                     u16* __restrict__ C2,
                                                     u16* __restrict__ C3) {
  __shared__ u16 Al[64 * 128];
  __shared__ u16 Bl[64 * 128];
  const int t = threadIdx.x;
  const int row0 = blockIdx.x * 64;

#pragma unroll
  for (int u = 0; u < 4; ++u) {
    int c = u * 256 + t;
    int r = c >> 4, ch = c & 15;
    int rc = (row0 + r < M) ? (row0 + r) : (M - 1);
    int sw = ch ^ (r & 7);
    *(u16x8*)&Al[r * 128 + sw * 8] = *(const u16x8*)(A + (size_t)rc * 128 + ch * 8);
  }

  const int w = t >> 6, lane = t & 63;
  const int lr = lane & 15, g = lane >> 4;
  const int arow = (w * 16 + lr) * 128;
  const int node = row0 + w * 16 + lr;   // this thread's output node (swapped D)

  u16x8 breg[4];
#pragma unroll
  for (int u = 0; u < 4; ++u) {
    int c = u * 256 + t;
    int r = c >> 4, ch = c & 15;
    breg[u] = *(const u16x8*)(W + r * 128 + ch * 8);
  }

  for (int ws = 0; ws < nw; ++ws) {
    u16* Cw = (ws == 0) ? C0 : (ws == 1) ? C1 : (ws == 2) ? C2 : C3;
#pragma unroll
    for (int h = 0; h < 2; ++h) {
      __builtin_amdgcn_sched_barrier(0);
      __builtin_amdgcn_s_barrier();
      __builtin_amdgcn_sched_barrier(0);
#pragma unroll
      for (int u = 0; u < 4; ++u) {
        int c = u * 256 + t;
        int r = c >> 4, ch = c & 15;
        int sw = ch ^ (r & 7);
        *(u16x8*)&Bl[r * 128 + sw * 8] = breg[u];
      }
      int nws = ws, nh = h + 1;
      if (nh == 2) { nh = 0; ++nws; }
      if (nws < nw) {
        const u16* Bn = W + (size_t)nws * 16384 + (size_t)nh * (64 * 128);
#pragma unroll
        for (int u = 0; u < 4; ++u) {
          int c = u * 256 + t;
          int r = c >> 4, ch = c & 15;
          breg[u] = *(const u16x8*)(Bn + r * 128 + ch * 8);
        }
      }
      asm volatile("s_waitcnt lgkmcnt(0)" ::: "memory");
      __builtin_amdgcn_sched_barrier(0);
      __builtin_amdgcn_s_barrier();
      __builtin_amdgcn_sched_barrier(0);

      f32x4 acc[4];
#pragma unroll
      for (int nf = 0; nf < 4; ++nf) acc[nf] = f32x4{0.f, 0.f, 0.f, 0.f};
#pragma unroll
      for (int ks = 0; ks < 4; ++ks) {
        int swz = ((ks * 4 + g) ^ (lr & 7)) * 8;
        s16x8 a = *(const s16x8*)&Al[arow + swz];
#pragma unroll
        for (int nf = 0; nf < 4; ++nf) {
          s16x8 b = *(const s16x8*)&Bl[(nf * 16 + lr) * 128 + swz];
          // swapped operands: D^T -> row = o-offset (g*4+j), col = node (lr)
          acc[nf] = __builtin_amdgcn_mfma_f32_16x16x32_bf16(b, a, acc[nf], 0, 0, 0);
        }
      }
      if (node < M) {
#pragma unroll
        for (int nf = 0; nf < 4; ++nf) {
          u16x4 o4;
#pragma unroll
          for (int j = 0; j < 4; ++j) o4[j] = f2b(acc[nf][j]);
          *(u16x4*)(Cw + (size_t)node * 128 + h * 64 + nf * 16 + g * 4) = o4;
        }
      }
    }
  }
}

// ---------------- fused dual-edge-type CSR aggregation (si-split subsegments):
// Y[d] = relu(HD0[d]+b0+max_{si=0}(HSA[s]+esf0[self]))
//      + relu(HD1[d]+b1+max_{si=1}(HSB[s]+esf1[self]))
__global__ __launch_bounds__(256) void agg2_k(const int* __restrict__ off2,
                                              const int* __restrict__ einfo,
                                              int segbase,
                                              const u16* __restrict__ HSA,
                                              const u16* __restrict__ HSB,
                                              const u16* __restrict__ HD0,
                                              const u16* __restrict__ HD1,
                                              const float* __restrict__ bs0,
                                              const float* __restrict__ bt0,
                                              const float* __restrict__ bs1,
                                              const float* __restrict__ bt1,
                                              const float* __restrict__ esf0,
                                              const float* __restrict__ esf1,
                                              u16* __restrict__ Y, int N) {
  int idx = blockIdx.x * 256 + threadIdx.x;
  int d = idx >> 4;                 // 16 threads per node, 8 features each
  if (d >= N) return;
  int f8 = (idx & 15) << 3;
  int base = (segbase + d) * 2;
  int e0 = off2[base], e1 = off2[base + 1], e2 = off2[base + 2];

  float en[8], es_[8];
#pragma unroll
  for (int k = 0; k < 8; ++k) { en[k] = esf0[f8 + k]; es_[k] = esf0[128 + f8 + k]; }
  float m0[8];
#pragma unroll
  for (int k = 0; k < 8; ++k) m0[k] = -INFINITY;
  for (int e = e0; e < e1; ++e) {
    int info = einfo[e];
    int s = info & 0x7fffffff;
    bool self = (info < 0);
    u16x8 hv = *(const u16x8*)(HSA + (size_t)s * 128 + f8);
#pragma unroll
    for (int k = 0; k < 8; ++k)
      m0[k] = fmaxf(m0[k], b2f(hv[k]) + (self ? es_[k] : en[k]));
  }

#pragma unroll
  for (int k = 0; k < 8; ++k) { en[k] = esf1[f8 + k]; es_[k] = esf1[128 + f8 + k]; }
  float m1[8];
#pragma unroll
  for (int k = 0; k < 8; ++k) m1[k] = -INFINITY;
  for (int e = e1; e < e2; ++e) {
    int info = einfo[e];
    int s = info & 0x7fffffff;
    bool self = (info < 0);
    u16x8 hv = *(const u16x8*)(HSB + (size_t)s * 128 + f8);
#pragma unroll
    for (int k = 0; k < 8; ++k)
      m1[k] = fmaxf(m1[k], b2f(hv[k]) + (self ? es_[k] : en[k]));
  }

  u16x8 hd0 = *(const u16x8*)(HD0 + (size_t)d * 128 + f8);
  u16x8 hd1 = *(const u16x8*)(HD1 + (size_t)d * 128 + f8);
  u16x8 o;
#pragma unroll
  for (int k = 0; k < 8; ++k) {
    float r0 = fmaxf(b2f(hd0[k]) + bs0[f8 + k] + bt0[f8 + k] + m0[k], 0.f);
    float r1 = fmaxf(b2f(hd1[k]) + bs1[f8 + k] + bt1[f8 + k] + m1[k], 0.f);
    o[k] = f2b(r0 + r1);
  }
  *(u16x8*)(Y + (size_t)d * 128 + f8) = o;
}

// ---------------- decoder + softmax -> FLOAT32 out: [logits | softmax]
__global__ __launch_bounds__(256) void decoder_k(const u16* __restrict__ X,
                                                 const float* __restrict__ Wd,
                                                 const float* __restrict__ bd,
                                                 float* __restrict__ out) {
  int v = blockIdx.x * 256 + threadIdx.x;
  if (v >= N0) return;
  float a0 = bd[0], a1 = bd[1], a2 = bd[2];
  const u16* x = X + (size_t)v * 128;
#pragma unroll
  for (int k = 0; k < 128; k += 8) {
    u16x8 xv = *(const u16x8*)(x + k);
#pragma unroll
    for (int u = 0; u < 8; ++u) {
      float xf = b2f(xv[u]);
      a0 = fmaf(xf, Wd[k + u], a0);
      a1 = fmaf(xf, Wd[128 + k + u], a1);
      a2 = fmaf(xf, Wd[256 + k + u], a2);
    }
  }
  float mx = fmaxf(a0, fmaxf(a1, a2));
  float e0 = expf(a0 - mx), e1 = expf(a1 - mx), e2 = expf(a2 - mx);
  float inv = 1.f / (e0 + e1 + e2);
  size_t b = (size_t)v * 3;
  out[b + 0] = a0; out[b + 1] = a1; out[b + 2] = a2;
  size_t b2 = (size_t)N0 * 3 + b;
  out[b2 + 0] = e0 * inv; out[b2 + 1] = e1 * inv; out[b2 + 2] = e2 * inv;
}

extern "C" void kernel_launch(void* const* d_in, const int* in_sizes, int n_in,
                              void* d_out, int out_size, void* d_ws, size_t ws_size,
                              hipStream_t stream) {
  float* out = (float*)d_out;

  // ---- sentinel 500: input-size assumption check
  const int expect[15] = {N0, N1, 2 * EE, 2 * EE, 2 * EE, 2 * EE,
                          NAL * 128, 128, 196608, 1536, 196608, 1536,
                          3072, 384, 3};
  bool ok = (n_in == 15);
  if (ok) for (int i = 0; i < 15; ++i) ok = ok && (in_sizes[i] == expect[i]);
  if (!ok) { sentinel_k<<<1, 64, 0, stream>>>(out, 500.f); return; }

  const int* x0_ids = (const int*)d_in[0];
  const int* x1_ids = (const int*)d_in[1];
  const int* es0 = (const int*)d_in[2];
  const int* es1 = (const int*)d_in[3];
  const int* es2 = (const int*)d_in[4];
  const int* es3 = (const int*)d_in[5];
  const float* enc_al   = (const float*)d_in[6];
  const float* emb_test = (const float*)d_in[7];
  const float* W_tgt    = (const float*)d_in[8];
  const float* b_tgt    = (const float*)d_in[9];
  const float* W_src    = (const float*)d_in[10];
  const float* b_src    = (const float*)d_in[11];
  const float* emb_self = (const float*)d_in[12];
  const float* W_dec    = (const float*)d_in[13];
  const float* b_dec    = (const float*)d_in[14];

  // ---- bump allocator (~238 MB < 256 MiB)
  char* base = (char*)d_ws;
  size_t pos = 0;
  auto alloc = [&](size_t bytes) -> void* {
    void* r = base + pos;
    pos += (bytes + 255) & ~(size_t)255;
    return r;
  };
  u16* xs0 = (u16*)alloc((size_t)N0 * 128 * 2);
  u16* xs1 = (u16*)alloc((size_t)N1 * 128 * 2);
  u16* P0  = (u16*)alloc((size_t)N0 * 128 * 2);   // t0 HSA  (Ws_j0 @ xs0)
  u16* P1  = (u16*)alloc((size_t)N0 * 128 * 2);   // HD0
  u16* P2  = (u16*)alloc((size_t)N0 * 128 * 2);   // HD1
  u16* P3  = (u16*)alloc((size_t)N1 * 128 * 2);   // HSB
  u16* P4  = (u16*)alloc((size_t)N0 * 128 * 2);   // t1 HSA  (Ws_j1 @ xs0)
  u16* BP  = (u16*)alloc((size_t)3 * 8 * 16384 * 2);
  int* off2   = (int*)alloc((size_t)(NSEG2 + 1) * 4);
  int* einfo  = (int*)alloc((size_t)TOTE * 4);
  int* counts = (int*)alloc((size_t)NSEG2 * 4);
  int* cursor = counts;                            // reuse: counts dead after scan1
  int* part   = (int*)alloc(1024 * 4);
  if (pos > ws_size) { sentinel_k<<<1, 64, 0, stream>>>(out, 900.f); return; }

  // ---- one-time prep
  prep_w<<<1536, 256, 0, stream>>>(W_src, W_tgt, BP);
  embed_k<<<(N0 * 16 + 255) / 256, 256, 0, stream>>>(x0_ids, enc_al, xs0, N0, NAL);
  embed_k<<<(N1 * 16 + 255) / 256, 256, 0, stream>>>(x1_ids, emb_test, xs1, N1, 1);

  // ---- merged si-split CSR build (once)
  const int EG = (TOTE + 255) / 256;             // 3125
  const int nb = (NSEG2 + 511) / 512;            // 879 <= 1024
  hipMemsetAsync(counts, 0, (size_t)NSEG2 * 4, stream);
  count_all<<<EG, 256, 0, stream>>>(es0, es1, es2, es3, counts);
  scan1_k<<<nb, 512, 0, stream>>>(counts, off2, part, NSEG2);
  scan2_k<<<1, 1024, 0, stream>>>(part, nb);
  scan3_k<<<(NSEG2 + 255) / 256, 256, 0, stream>>>(off2, part, NSEG2, TOTE);
  hipMemsetAsync(cursor, 0, (size_t)NSEG2 * 4, stream);
  fill_all<<<EG, 256, 0, stream>>>(es0, es1, es2, es3, off2, cursor, einfo);

  // ---- layers (agg writes in-place into xs; xs consumed by GEMMs first)
  const int G0 = (N0 + 63) / 64, G1 = (N1 + 63) / 64;
  const int GA0 = (N0 * 16 + 255) / 256, GA1 = (N1 * 16 + 255) / 256;
  for (int i = 0; i < 3; ++i) {
    const u16* BPi = BP + (size_t)i * 8 * 16384;
    // one pass over xs0: Ws_j0, Wt_j0, Wt_j2 (+ Ws_j1 if t1 needed)
    gemm_multi<<<G0, 256, 0, stream>>>(xs0, N0, BPi + 0 * 16384, (i < 2) ? 4 : 3,
                                       P0, P1, P2, P4);
    gemm_multi<<<G1, 256, 0, stream>>>(xs1, N1, BPi + 4 * 16384, 1, P3, P3, P3, P3);
    agg2_k<<<GA0, 256, 0, stream>>>(off2, einfo, 0, P0, P3, P1, P2,
                                    b_src + (size_t)(i * 4 + 0) * 128, b_tgt + (size_t)(i * 4 + 0) * 128,
                                    b_src + (size_t)(i * 4 + 2) * 128, b_tgt + (size_t)(i * 4 + 2) * 128,
                                    emb_self + (size_t)(i * 4 + 0) * 256,
                                    emb_self + (size_t)(i * 4 + 2) * 256, xs0, N0);
    if (i < 2) {
      // one pass over xs1: Ws_j3, Wt_j1, Wt_j3 (P3/P1/P2 free after agg t0)
      gemm_multi<<<G1, 256, 0, stream>>>(xs1, N1, BPi + 5 * 16384, 3, P3, P1, P2, P2);
      agg2_k<<<GA1, 256, 0, stream>>>(off2, einfo, N0, P4, P3, P1, P2,
                                      b_src + (size_t)(i * 4 + 1) * 128, b_tgt + (size_t)(i * 4 + 1) * 128,
                                      b_src + (size_t)(i * 4 + 3) * 128, b_tgt + (size_t)(i * 4 + 3) * 128,
                                      emb_self + (size_t)(i * 4 + 1) * 256,
                                      emb_self + (size_t)(i * 4 + 3) * 256, xs1, N1);
    }
  }

  decoder_k<<<(N0 + 255) / 256, 256, 0, stream>>>(xs0, W_dec, b_dec, out);
}

// Round 18
// 491.359 us; speedup vs baseline: 1.1698x; 1.1698x over previous
//
#include <hip/hip_runtime.h>
#include <hip/hip_bf16.h>

// Problem constants
#define N0 150000
#define N1 75000
#define EE 200000
#define NAL 50000
#define NSEG (N0 + N1)
#define NSEG2 (2 * NSEG)
#define TOTE (4 * EE)

typedef unsigned short u16;
using s16x8 = __attribute__((ext_vector_type(8))) short;
using f32x4 = __attribute__((ext_vector_type(4))) float;
using u16x8 = __attribute__((ext_vector_type(8))) unsigned short;

__device__ __forceinline__ u16 f2b(float f) {
  unsigned int b = __float_as_uint(f);
  b += 0x7FFFu + ((b >> 16) & 1u);   // RNE
  return (u16)(b >> 16);
}
__device__ __forceinline__ float b2f(u16 u) {
  return __uint_as_float(((unsigned int)u) << 16);
}

// ---------------- diagnostic sentinel (f32 out)
__global__ void sentinel_k(float* out, float val) {
  if (threadIdx.x == 0 && blockIdx.x == 0) out[0] = val;
}

// ---------------- pack weights bf16: BP[i][slot][o][k]
// slot order: 0:Ws_j0 1:Wt_j0 2:Wt_j2 3:Ws_j1 4:Ws_j2 5:Ws_j3 6:Wt_j1 7:Wt_j3
__global__ __launch_bounds__(256) void prep_w(const float* __restrict__ Ws,
                                              const float* __restrict__ Wt,
                                              u16* __restrict__ BP) {
  int idx = blockIdx.x * 256 + threadIdx.x;   // grid covers 3*8*16384 exactly
  int mk = idx & 16383;
  int slot = (idx >> 14) & 7;
  int i = idx >> 17;
  const int ssel[8] = {1, 0, 0, 1, 1, 1, 0, 0};
  const int sj[8]   = {0, 0, 2, 1, 2, 3, 1, 3};
  const float* W = ssel[slot] ? Ws : Wt;
  BP[idx] = f2b(W[(size_t)(i * 4 + sj[slot]) * 16384 + mk]);
}

// ---------------- embedding gather -> bf16 xs (both node types, one launch)
__global__ __launch_bounds__(256) void embed2_k(const int* __restrict__ ids0,
                                                const int* __restrict__ ids1,
                                                const float* __restrict__ tab0,
                                                const float* __restrict__ tab1,
                                                u16* __restrict__ X0,
                                                u16* __restrict__ X1) {
  int idx = blockIdx.x * 256 + threadIdx.x;
  int v = idx >> 4;
  const int* ids; const float* tab; u16* X; unsigned vocab;
  if (v < N0) { ids = ids0; tab = tab0; X = X0; vocab = NAL; }
  else if (v < N0 + N1) { v -= N0; ids = ids1; tab = tab1; X = X1; vocab = 1; }
  else return;
  int q = (idx & 15) << 3;
  unsigned id = (unsigned)ids[v];
  if (id >= vocab) id = 0;          // defensive
  const float* src = tab + (size_t)id * 128 + q;
  f32x4 x0 = *(const f32x4*)src;
  f32x4 x1 = *(const f32x4*)(src + 4);
  u16x8 o;
#pragma unroll
  for (int k = 0; k < 4; ++k) { o[k] = f2b(x0[k]); o[4 + k] = f2b(x1[k]); }
  *(u16x8*)(X + (size_t)v * 128 + q) = o;
}

// ---------------- merged CSR build, split by si: seg2 = 2*(dst or N0+dst) + (j>>1)
__global__ __launch_bounds__(256) void count_all(const int* __restrict__ e0,
                                                 const int* __restrict__ e1,
                                                 const int* __restrict__ e2,
                                                 const int* __restrict__ e3,
                                                 int* __restrict__ cnt) {
  int i = blockIdx.x * 256 + threadIdx.x;
  if (i >= TOTE) return;
  int j = i / EE, r = i - j * EE;
  const int* es = (j == 0) ? e0 : (j == 1) ? e1 : (j == 2) ? e2 : e3;
  int dst = es[EE + r];
  int seg = (j & 1) ? N0 + dst : dst;
  atomicAdd(cnt + seg * 2 + (j >> 1), 1);
}

// 512-thread scan blocks so NSEG2=450000 -> 879 partials (<=1024)
__global__ __launch_bounds__(512) void scan1_k(const int* __restrict__ cnt,
                                               int* __restrict__ off,
                                               int* __restrict__ part, int N) {
  __shared__ int sh[512];
  int t = threadIdx.x, i = blockIdx.x * 512 + t;
  int v = (i < N) ? cnt[i] : 0;
  sh[t] = v; __syncthreads();
  for (int s = 1; s < 512; s <<= 1) {
    int x = (t >= s) ? sh[t - s] : 0; __syncthreads();
    sh[t] += x; __syncthreads();
  }
  if (i < N) off[i] = sh[t] - v;                 // exclusive within block
  if (t == 511) part[blockIdx.x] = sh[511];      // block total
}

__global__ __launch_bounds__(1024) void scan2_k(int* __restrict__ part, int n) {
  __shared__ int sh[1024];
  int t = threadIdx.x;
  int v = (t < n) ? part[t] : 0;
  sh[t] = v; __syncthreads();
  for (int s = 1; s < 1024; s <<= 1) {
    int x = (t >= s) ? sh[t - s] : 0; __syncthreads();
    sh[t] += x; __syncthreads();
  }
  if (t < n) part[t] = sh[t] - v;                // exclusive
}

__global__ __launch_bounds__(256) void scan3_k(int* __restrict__ off,
                                               const int* __restrict__ part, int N, int tot) {
  int i = blockIdx.x * 256 + threadIdx.x;
  if (i < N) off[i] += part[i >> 9];
  if (i == 0) off[N] = tot;
}

// einfo[pos] = src | (self << 31); si is implied by subsegment range
__global__ __launch_bounds__(256) void fill_all(const int* __restrict__ e0,
                                                const int* __restrict__ e1,
                                                const int* __restrict__ e2,
                                                const int* __restrict__ e3,
                                                const int* __restrict__ off,
                                                int* __restrict__ cur,
                                                int* __restrict__ einfo) {
  int i = blockIdx.x * 256 + threadIdx.x;
  if (i >= TOTE) return;
  int j = i / EE, r = i - j * EE;
  const int* es = (j == 0) ? e0 : (j == 1) ? e1 : (j == 2) ? e2 : e3;
  int src = es[r], dst = es[EE + r];
  int seg2 = ((j & 1) ? N0 + dst : dst) * 2 + (j >> 1);
  int pos = off[seg2] + atomicAdd(cur + seg2, 1);
  einfo[pos] = src | ((src == dst) ? (int)0x80000000 : 0);
}

// ---------------- dual-staged multi-weight MFMA GEMM, half-B staging (r14 inner
// code UNCHANGED), now two-segment: blocks < nB0 -> A0/M0/nw0 (4 outputs);
// blocks >= nB0 -> A1/M1, 1 slot -> C10. Both segments use identical LDS
// staging (the r13 failure was A-direct loads, not the fusion).
__global__ __launch_bounds__(256, 5) void gemm_fused(const u16* __restrict__ A0, int M0, int nB0,
                                                     const u16* __restrict__ W0, int nw0,
                                                     u16* __restrict__ C00, u16* __restrict__ C01,
                                                     u16* __restrict__ C02, u16* __restrict__ C03,
                                                     const u16* __restrict__ A1, int M1,
                                                     const u16* __restrict__ W1,
                                                     u16* __restrict__ C10) {
  __shared__ u16 Al[64 * 128];
  __shared__ u16 Bl[64 * 128];
  const int t = threadIdx.x;
  const u16* A; const u16* W; int M, row0, nw;
  u16 *c0, *c1, *c2, *c3;
  if ((int)blockIdx.x < nB0) {
    A = A0; M = M0; row0 = blockIdx.x * 64; W = W0; nw = nw0;
    c0 = C00; c1 = C01; c2 = C02; c3 = C03;
  } else {
    A = A1; M = M1; row0 = (blockIdx.x - nB0) * 64; W = W1; nw = 1;
    c0 = C10; c1 = C10; c2 = C10; c3 = C10;
  }

  // stage A (clamped rows for the tail block; stores guarded later)
#pragma unroll
  for (int u = 0; u < 4; ++u) {
    int c = u * 256 + t;
    int r = c >> 4, ch = c & 15;
    int rc = (row0 + r < M) ? (row0 + r) : (M - 1);
    int sw = ch ^ (r & 7);
    *(u16x8*)&Al[r * 128 + sw * 8] = *(const u16x8*)(A + (size_t)rc * 128 + ch * 8);
  }

  const int w = t >> 6, lane = t & 63;
  const int lr = lane & 15, g = lane >> 4;
  const int arow = (w * 16 + lr) * 128;   // wave w owns rows w*16..w*16+15

  // preload B (slot 0, half 0) into regs
  u16x8 breg[4];
#pragma unroll
  for (int u = 0; u < 4; ++u) {
    int c = u * 256 + t;
    int r = c >> 4, ch = c & 15;
    breg[u] = *(const u16x8*)(W + r * 128 + ch * 8);
  }

  for (int ws = 0; ws < nw; ++ws) {
    u16* Cw = (ws == 0) ? c0 : (ws == 1) ? c1 : (ws == 2) ? c2 : c3;
#pragma unroll
    for (int h = 0; h < 2; ++h) {
      __builtin_amdgcn_sched_barrier(0);
      __builtin_amdgcn_s_barrier();
      __builtin_amdgcn_sched_barrier(0);
#pragma unroll
      for (int u = 0; u < 4; ++u) {
        int c = u * 256 + t;
        int r = c >> 4, ch = c & 15;
        int sw = ch ^ (r & 7);
        *(u16x8*)&Bl[r * 128 + sw * 8] = breg[u];
      }
      int nws = ws, nh = h + 1;
      if (nh == 2) { nh = 0; ++nws; }
      if (nws < nw) {
        const u16* Bn = W + (size_t)nws * 16384 + (size_t)nh * (64 * 128);
#pragma unroll
        for (int u = 0; u < 4; ++u) {
          int c = u * 256 + t;
          int r = c >> 4, ch = c & 15;
          breg[u] = *(const u16x8*)(Bn + r * 128 + ch * 8);
        }
      }
      asm volatile("s_waitcnt lgkmcnt(0)" ::: "memory");
      __builtin_amdgcn_sched_barrier(0);
      __builtin_amdgcn_s_barrier();
      __builtin_amdgcn_sched_barrier(0);

      f32x4 acc[4];
#pragma unroll
      for (int nf = 0; nf < 4; ++nf) acc[nf] = f32x4{0.f, 0.f, 0.f, 0.f};
#pragma unroll
      for (int ks = 0; ks < 4; ++ks) {
        int swz = ((ks * 4 + g) ^ (lr & 7)) * 8;
        s16x8 a = *(const s16x8*)&Al[arow + swz];
#pragma unroll
        for (int nf = 0; nf < 4; ++nf) {
          s16x8 b = *(const s16x8*)&Bl[(nf * 16 + lr) * 128 + swz];
          acc[nf] = __builtin_amdgcn_mfma_f32_16x16x32_bf16(a, b, acc[nf], 0, 0, 0);
        }
      }
#pragma unroll
      for (int nf = 0; nf < 4; ++nf) {
        int col = h * 64 + nf * 16 + lr;
#pragma unroll
        for (int j = 0; j < 4; ++j) {
          int orow = row0 + w * 16 + g * 4 + j;
          if (orow < M) Cw[(size_t)orow * 128 + col] = f2b(acc[nf][j]);
        }
      }
    }
  }
}

// ---------------- fused dual-edge-type CSR aggregation (si-split subsegments):
// Y[d] = relu(HD0[d]+b0+max_{si=0}(HSA[s]+esf0[self]))
//      + relu(HD1[d]+b1+max_{si=1}(HSB[s]+esf1[self]))
__global__ __launch_bounds__(256) void agg2_k(const int* __restrict__ off2,
                                              const int* __restrict__ einfo,
                                              int segbase,
                                              const u16* __restrict__ HSA,
                                              const u16* __restrict__ HSB,
                                              const u16* __restrict__ HD0,
                                              const u16* __restrict__ HD1,
                                              const float* __restrict__ bs0,
                                              const float* __restrict__ bt0,
                                              const float* __restrict__ bs1,
                                              const float* __restrict__ bt1,
                                              const float* __restrict__ esf0,
                                              const float* __restrict__ esf1,
                                              u16* __restrict__ Y, int N) {
  int idx = blockIdx.x * 256 + threadIdx.x;
  int d = idx >> 4;                 // 16 threads per node, 8 features each
  if (d >= N) return;
  int f8 = (idx & 15) << 3;
  int base = (segbase + d) * 2;
  int e0 = off2[base], e1 = off2[base + 1], e2 = off2[base + 2];

  float en[8], es_[8];
#pragma unroll
  for (int k = 0; k < 8; ++k) { en[k] = esf0[f8 + k]; es_[k] = esf0[128 + f8 + k]; }
  float m0[8];
#pragma unroll
  for (int k = 0; k < 8; ++k) m0[k] = -INFINITY;
  for (int e = e0; e < e1; ++e) {
    int info = einfo[e];
    int s = info & 0x7fffffff;
    bool self = (info < 0);
    u16x8 hv = *(const u16x8*)(HSA + (size_t)s * 128 + f8);
#pragma unroll
    for (int k = 0; k < 8; ++k)
      m0[k] = fmaxf(m0[k], b2f(hv[k]) + (self ? es_[k] : en[k]));
  }

#pragma unroll
  for (int k = 0; k < 8; ++k) { en[k] = esf1[f8 + k]; es_[k] = esf1[128 + f8 + k]; }
  float m1[8];
#pragma unroll
  for (int k = 0; k < 8; ++k) m1[k] = -INFINITY;
  for (int e = e1; e < e2; ++e) {
    int info = einfo[e];
    int s = info & 0x7fffffff;
    bool self = (info < 0);
    u16x8 hv = *(const u16x8*)(HSB + (size_t)s * 128 + f8);
#pragma unroll
    for (int k = 0; k < 8; ++k)
      m1[k] = fmaxf(m1[k], b2f(hv[k]) + (self ? es_[k] : en[k]));
  }

  u16x8 hd0 = *(const u16x8*)(HD0 + (size_t)d * 128 + f8);
  u16x8 hd1 = *(const u16x8*)(HD1 + (size_t)d * 128 + f8);
  u16x8 o;
#pragma unroll
  for (int k = 0; k < 8; ++k) {
    float r0 = fmaxf(b2f(hd0[k]) + bs0[f8 + k] + bt0[f8 + k] + m0[k], 0.f);
    float r1 = fmaxf(b2f(hd1[k]) + bs1[f8 + k] + bt1[f8 + k] + m1[k], 0.f);
    o[k] = f2b(r0 + r1);
  }
  *(u16x8*)(Y + (size_t)d * 128 + f8) = o;
}

// ---------------- decoder + softmax -> FLOAT32 out: [logits | softmax]
__global__ __launch_bounds__(256) void decoder_k(const u16* __restrict__ X,
                                                 const float* __restrict__ Wd,
                                                 const float* __restrict__ bd,
                                                 float* __restrict__ out) {
  int v = blockIdx.x * 256 + threadIdx.x;
  if (v >= N0) return;
  float a0 = bd[0], a1 = bd[1], a2 = bd[2];
  const u16* x = X + (size_t)v * 128;
#pragma unroll
  for (int k = 0; k < 128; k += 8) {
    u16x8 xv = *(const u16x8*)(x + k);
#pragma unroll
    for (int u = 0; u < 8; ++u) {
      float xf = b2f(xv[u]);
      a0 = fmaf(xf, Wd[k + u], a0);
      a1 = fmaf(xf, Wd[128 + k + u], a1);
      a2 = fmaf(xf, Wd[256 + k + u], a2);
    }
  }
  float mx = fmaxf(a0, fmaxf(a1, a2));
  float e0 = expf(a0 - mx), e1 = expf(a1 - mx), e2 = expf(a2 - mx);
  float inv = 1.f / (e0 + e1 + e2);
  size_t b = (size_t)v * 3;
  out[b + 0] = a0; out[b + 1] = a1; out[b + 2] = a2;
  size_t b2 = (size_t)N0 * 3 + b;
  out[b2 + 0] = e0 * inv; out[b2 + 1] = e1 * inv; out[b2 + 2] = e2 * inv;
}

extern "C" void kernel_launch(void* const* d_in, const int* in_sizes, int n_in,
                              void* d_out, int out_size, void* d_ws, size_t ws_size,
                              hipStream_t stream) {
  float* out = (float*)d_out;

  // ---- sentinel 500: input-size assumption check
  const int expect[15] = {N0, N1, 2 * EE, 2 * EE, 2 * EE, 2 * EE,
                          NAL * 128, 128, 196608, 1536, 196608, 1536,
                          3072, 384, 3};
  bool ok = (n_in == 15);
  if (ok) for (int i = 0; i < 15; ++i) ok = ok && (in_sizes[i] == expect[i]);
  if (!ok) { sentinel_k<<<1, 64, 0, stream>>>(out, 500.f); return; }

  const int* x0_ids = (const int*)d_in[0];
  const int* x1_ids = (const int*)d_in[1];
  const int* es0 = (const int*)d_in[2];
  const int* es1 = (const int*)d_in[3];
  const int* es2 = (const int*)d_in[4];
  const int* es3 = (const int*)d_in[5];
  const float* enc_al   = (const float*)d_in[6];
  const float* emb_test = (const float*)d_in[7];
  const float* W_tgt    = (const float*)d_in[8];
  const float* b_tgt    = (const float*)d_in[9];
  const float* W_src    = (const float*)d_in[10];
  const float* b_src    = (const float*)d_in[11];
  const float* emb_self = (const float*)d_in[12];
  const float* W_dec    = (const float*)d_in[13];
  const float* b_dec    = (const float*)d_in[14];

  // ---- bump allocator (~238 MB < 256 MiB)
  char* base = (char*)d_ws;
  size_t pos = 0;
  auto alloc = [&](size_t bytes) -> void* {
    void* r = base + pos;
    pos += (bytes + 255) & ~(size_t)255;
    return r;
  };
  u16* xs0 = (u16*)alloc((size_t)N0 * 128 * 2);
  u16* xs1 = (u16*)alloc((size_t)N1 * 128 * 2);
  u16* P0  = (u16*)alloc((size_t)N0 * 128 * 2);   // t0 HSA  (Ws_j0 @ xs0)
  u16* P1  = (u16*)alloc((size_t)N0 * 128 * 2);   // HD0
  u16* P2  = (u16*)alloc((size_t)N0 * 128 * 2);   // HD1
  u16* P3  = (u16*)alloc((size_t)N1 * 128 * 2);   // HSB
  u16* P4  = (u16*)alloc((size_t)N0 * 128 * 2);   // t1 HSA  (Ws_j1 @ xs0)
  u16* BP  = (u16*)alloc((size_t)3 * 8 * 16384 * 2);
  int* off2   = (int*)alloc((size_t)(NSEG2 + 1) * 4);
  int* einfo  = (int*)alloc((size_t)TOTE * 4);
  int* counts = (int*)alloc((size_t)NSEG2 * 4);
  int* cursor = counts;                            // reuse: counts dead after scan1
  int* part   = (int*)alloc(1024 * 4);
  if (pos > ws_size) { sentinel_k<<<1, 64, 0, stream>>>(out, 900.f); return; }

  // ---- one-time prep
  prep_w<<<1536, 256, 0, stream>>>(W_src, W_tgt, BP);
  embed2_k<<<((N0 + N1) * 16 + 255) / 256, 256, 0, stream>>>(x0_ids, x1_ids, enc_al, emb_test, xs0, xs1);

  // ---- merged si-split CSR build (once)
  const int EG = (TOTE + 255) / 256;             // 3125
  const int nb = (NSEG2 + 511) / 512;            // 879 <= 1024
  hipMemsetAsync(counts, 0, (size_t)NSEG2 * 4, stream);
  count_all<<<EG, 256, 0, stream>>>(es0, es1, es2, es3, counts);
  scan1_k<<<nb, 512, 0, stream>>>(counts, off2, part, NSEG2);
  scan2_k<<<1, 1024, 0, stream>>>(part, nb);
  scan3_k<<<(NSEG2 + 255) / 256, 256, 0, stream>>>(off2, part, NSEG2, TOTE);
  hipMemsetAsync(cursor, 0, (size_t)NSEG2 * 4, stream);
  fill_all<<<EG, 256, 0, stream>>>(es0, es1, es2, es3, off2, cursor, einfo);

  // ---- layers (agg writes in-place into xs; xs consumed by GEMMs first)
  const int G0 = (N0 + 63) / 64, G1 = (N1 + 63) / 64;
  const int GA0 = (N0 * 16 + 255) / 256, GA1 = (N1 * 16 + 255) / 256;
  for (int i = 0; i < 3; ++i) {
    const u16* BPi = BP + (size_t)i * 8 * 16384;
    // fused: seg0 = xs0 {Ws_j0, Wt_j0, Wt_j2 (,Ws_j1)}; seg1 = xs1 {Ws_j2 -> P3}
    gemm_fused<<<G0 + G1, 256, 0, stream>>>(xs0, N0, G0, BPi + 0 * 16384, (i < 2) ? 4 : 3,
                                            P0, P1, P2, P4,
                                            xs1, N1, BPi + 4 * 16384, P3);
    agg2_k<<<GA0, 256, 0, stream>>>(off2, einfo, 0, P0, P3, P1, P2,
                                    b_src + (size_t)(i * 4 + 0) * 128, b_tgt + (size_t)(i * 4 + 0) * 128,
                                    b_src + (size_t)(i * 4 + 2) * 128, b_tgt + (size_t)(i * 4 + 2) * 128,
                                    emb_self + (size_t)(i * 4 + 0) * 256,
                                    emb_self + (size_t)(i * 4 + 2) * 256, xs0, N0);
    if (i < 2) {
      // xs1 pass: Ws_j3 -> P3, Wt_j1 -> P1, Wt_j3 -> P2 (second segment inert:
      // grid == nB0, so no block enters it)
      gemm_fused<<<G1, 256, 0, stream>>>(xs1, N1, G1, BPi + 5 * 16384, 3,
                                         P3, P1, P2, P2,
                                         xs1, N1, BPi + 4 * 16384, P3);
      agg2_k<<<GA1, 256, 0, stream>>>(off2, einfo, N0, P4, P3, P1, P2,
                                      b_src + (size_t)(i * 4 + 1) * 128, b_tgt + (size_t)(i * 4 + 1) * 128,
                                      b_src + (size_t)(i * 4 + 3) * 128, b_tgt + (size_t)(i * 4 + 3) * 128,
                                      emb_self + (size_t)(i * 4 + 1) * 256,
                                      emb_self + (size_t)(i * 4 + 3) * 256, xs1, N1);
    }
  }

  decoder_k<<<(N0 + 255) / 256, 256, 0, stream>>>(xs0, W_dec, b_dec, out);
}

// Round 19
// 472.090 us; speedup vs baseline: 1.2176x; 1.0408x over previous
//
#include <hip/hip_runtime.h>
#include <hip/hip_bf16.h>

// Problem constants
#define N0 150000
#define N1 75000
#define EE 200000
#define NAL 50000
#define NSEG (N0 + N1)
#define NSEG2 (2 * NSEG)
#define TOTE (4 * EE)

typedef unsigned short u16;
using s16x8 = __attribute__((ext_vector_type(8))) short;
using f32x4 = __attribute__((ext_vector_type(4))) float;
using u16x8 = __attribute__((ext_vector_type(8))) unsigned short;

__device__ __forceinline__ u16 f2b(float f) {
  unsigned int b = __float_as_uint(f);
  b += 0x7FFFu + ((b >> 16) & 1u);   // RNE
  return (u16)(b >> 16);
}
__device__ __forceinline__ float b2f(u16 u) {
  return __uint_as_float(((unsigned int)u) << 16);
}

// ---------------- diagnostic sentinel (f32 out)
__global__ void sentinel_k(float* out, float val) {
  if (threadIdx.x == 0 && blockIdx.x == 0) out[0] = val;
}

// ---------------- pack weights bf16: BP[i][slot][o][k]
// slot order: 0:Ws_j0 1:Wt_j0 2:Wt_j2 3:Ws_j1 4:Ws_j2 5:Ws_j3 6:Wt_j1 7:Wt_j3
__global__ __launch_bounds__(256) void prep_w(const float* __restrict__ Ws,
                                              const float* __restrict__ Wt,
                                              u16* __restrict__ BP) {
  int idx = blockIdx.x * 256 + threadIdx.x;   // grid covers 3*8*16384 exactly
  int mk = idx & 16383;
  int slot = (idx >> 14) & 7;
  int i = idx >> 17;
  const int ssel[8] = {1, 0, 0, 1, 1, 1, 0, 0};
  const int sj[8]   = {0, 0, 2, 1, 2, 3, 1, 3};
  const float* W = ssel[slot] ? Ws : Wt;
  BP[idx] = f2b(W[(size_t)(i * 4 + sj[slot]) * 16384 + mk]);
}

// ---------------- embedding gather -> bf16 xs (both node types, one launch)
__global__ __launch_bounds__(256) void embed2_k(const int* __restrict__ ids0,
                                                const int* __restrict__ ids1,
                                                const float* __restrict__ tab0,
                                                const float* __restrict__ tab1,
                                                u16* __restrict__ X0,
                                                u16* __restrict__ X1) {
  int idx = blockIdx.x * 256 + threadIdx.x;
  int v = idx >> 4;
  const int* ids; const float* tab; u16* X; unsigned vocab;
  if (v < N0) { ids = ids0; tab = tab0; X = X0; vocab = NAL; }
  else if (v < N0 + N1) { v -= N0; ids = ids1; tab = tab1; X = X1; vocab = 1; }
  else return;
  int q = (idx & 15) << 3;
  unsigned id = (unsigned)ids[v];
  if (id >= vocab) id = 0;          // defensive
  const float* src = tab + (size_t)id * 128 + q;
  f32x4 x0 = *(const f32x4*)src;
  f32x4 x1 = *(const f32x4*)(src + 4);
  u16x8 o;
#pragma unroll
  for (int k = 0; k < 4; ++k) { o[k] = f2b(x0[k]); o[4 + k] = f2b(x1[k]); }
  *(u16x8*)(X + (size_t)v * 128 + q) = o;
}

// ---------------- merged CSR build, split by si: seg2 = 2*(dst or N0+dst) + (j>>1)
__global__ __launch_bounds__(256) void count_all(const int* __restrict__ e0,
                                                 const int* __restrict__ e1,
                                                 const int* __restrict__ e2,
                                                 const int* __restrict__ e3,
                                                 int* __restrict__ cnt) {
  int i = blockIdx.x * 256 + threadIdx.x;
  if (i >= TOTE) return;
  int j = i / EE, r = i - j * EE;
  const int* es = (j == 0) ? e0 : (j == 1) ? e1 : (j == 2) ? e2 : e3;
  int dst = es[EE + r];
  int seg = (j & 1) ? N0 + dst : dst;
  atomicAdd(cnt + seg * 2 + (j >> 1), 1);
}

// 512-thread scan blocks so NSEG2=450000 -> 879 partials (<=1024)
__global__ __launch_bounds__(512) void scan1_k(const int* __restrict__ cnt,
                                               int* __restrict__ off,
                                               int* __restrict__ part, int N) {
  __shared__ int sh[512];
  int t = threadIdx.x, i = blockIdx.x * 512 + t;
  int v = (i < N) ? cnt[i] : 0;
  sh[t] = v; __syncthreads();
  for (int s = 1; s < 512; s <<= 1) {
    int x = (t >= s) ? sh[t - s] : 0; __syncthreads();
    sh[t] += x; __syncthreads();
  }
  if (i < N) off[i] = sh[t] - v;                 // exclusive within block
  if (t == 511) part[blockIdx.x] = sh[511];      // block total
}

__global__ __launch_bounds__(1024) void scan2_k(int* __restrict__ part, int n) {
  __shared__ int sh[1024];
  int t = threadIdx.x;
  int v = (t < n) ? part[t] : 0;
  sh[t] = v; __syncthreads();
  for (int s = 1; s < 1024; s <<= 1) {
    int x = (t >= s) ? sh[t - s] : 0; __syncthreads();
    sh[t] += x; __syncthreads();
  }
  if (t < n) part[t] = sh[t] - v;                // exclusive
}

__global__ __launch_bounds__(256) void scan3_k(int* __restrict__ off,
                                               const int* __restrict__ part, int N, int tot) {
  int i = blockIdx.x * 256 + threadIdx.x;
  if (i < N) off[i] += part[i >> 9];
  if (i == 0) off[N] = tot;
}

// einfo[pos] = src | (self << 31); si is implied by subsegment range
__global__ __launch_bounds__(256) void fill_all(const int* __restrict__ e0,
                                                const int* __restrict__ e1,
                                                const int* __restrict__ e2,
                                                const int* __restrict__ e3,
                                                const int* __restrict__ off,
                                                int* __restrict__ cur,
                                                int* __restrict__ einfo) {
  int i = blockIdx.x * 256 + threadIdx.x;
  if (i >= TOTE) return;
  int j = i / EE, r = i - j * EE;
  const int* es = (j == 0) ? e0 : (j == 1) ? e1 : (j == 2) ? e2 : e3;
  int src = es[r], dst = es[EE + r];
  int seg2 = ((j & 1) ? N0 + dst : dst) * 2 + (j >> 1);
  int pos = off[seg2] + atomicAdd(cur + seg2, 1);
  einfo[pos] = src | ((src == dst) ? (int)0x80000000 : 0);
}

// ---------------- dual-staged multi-weight MFMA GEMM, half-B staging (r14 inner
// code UNCHANGED), two-segment (r18): blocks < nB0 -> A0/M0/nw0 (4 outputs);
// blocks >= nB0 -> A1/M1, 1 slot -> C10.
__global__ __launch_bounds__(256, 5) void gemm_fused(const u16* __restrict__ A0, int M0, int nB0,
                                                     const u16* __restrict__ W0, int nw0,
                                                     u16* __restrict__ C00, u16* __restrict__ C01,
                                                     u16* __restrict__ C02, u16* __restrict__ C03,
                                                     const u16* __restrict__ A1, int M1,
                                                     const u16* __restrict__ W1,
                                                     u16* __restrict__ C10) {
  __shared__ u16 Al[64 * 128];
  __shared__ u16 Bl[64 * 128];
  const int t = threadIdx.x;
  const u16* A; const u16* W; int M, row0, nw;
  u16 *c0, *c1, *c2, *c3;
  if ((int)blockIdx.x < nB0) {
    A = A0; M = M0; row0 = blockIdx.x * 64; W = W0; nw = nw0;
    c0 = C00; c1 = C01; c2 = C02; c3 = C03;
  } else {
    A = A1; M = M1; row0 = (blockIdx.x - nB0) * 64; W = W1; nw = 1;
    c0 = C10; c1 = C10; c2 = C10; c3 = C10;
  }

  // stage A (clamped rows for the tail block; stores guarded later)
#pragma unroll
  for (int u = 0; u < 4; ++u) {
    int c = u * 256 + t;
    int r = c >> 4, ch = c & 15;
    int rc = (row0 + r < M) ? (row0 + r) : (M - 1);
    int sw = ch ^ (r & 7);
    *(u16x8*)&Al[r * 128 + sw * 8] = *(const u16x8*)(A + (size_t)rc * 128 + ch * 8);
  }

  const int w = t >> 6, lane = t & 63;
  const int lr = lane & 15, g = lane >> 4;
  const int arow = (w * 16 + lr) * 128;   // wave w owns rows w*16..w*16+15

  // preload B (slot 0, half 0) into regs
  u16x8 breg[4];
#pragma unroll
  for (int u = 0; u < 4; ++u) {
    int c = u * 256 + t;
    int r = c >> 4, ch = c & 15;
    breg[u] = *(const u16x8*)(W + r * 128 + ch * 8);
  }

  for (int ws = 0; ws < nw; ++ws) {
    u16* Cw = (ws == 0) ? c0 : (ws == 1) ? c1 : (ws == 2) ? c2 : c3;
#pragma unroll
    for (int h = 0; h < 2; ++h) {
      __builtin_amdgcn_sched_barrier(0);
      __builtin_amdgcn_s_barrier();
      __builtin_amdgcn_sched_barrier(0);
#pragma unroll
      for (int u = 0; u < 4; ++u) {
        int c = u * 256 + t;
        int r = c >> 4, ch = c & 15;
        int sw = ch ^ (r & 7);
        *(u16x8*)&Bl[r * 128 + sw * 8] = breg[u];
      }
      int nws = ws, nh = h + 1;
      if (nh == 2) { nh = 0; ++nws; }
      if (nws < nw) {
        const u16* Bn = W + (size_t)nws * 16384 + (size_t)nh * (64 * 128);
#pragma unroll
        for (int u = 0; u < 4; ++u) {
          int c = u * 256 + t;
          int r = c >> 4, ch = c & 15;
          breg[u] = *(const u16x8*)(Bn + r * 128 + ch * 8);
        }
      }
      asm volatile("s_waitcnt lgkmcnt(0)" ::: "memory");
      __builtin_amdgcn_sched_barrier(0);
      __builtin_amdgcn_s_barrier();
      __builtin_amdgcn_sched_barrier(0);

      f32x4 acc[4];
#pragma unroll
      for (int nf = 0; nf < 4; ++nf) acc[nf] = f32x4{0.f, 0.f, 0.f, 0.f};
#pragma unroll
      for (int ks = 0; ks < 4; ++ks) {
        int swz = ((ks * 4 + g) ^ (lr & 7)) * 8;
        s16x8 a = *(const s16x8*)&Al[arow + swz];
#pragma unroll
        for (int nf = 0; nf < 4; ++nf) {
          s16x8 b = *(const s16x8*)&Bl[(nf * 16 + lr) * 128 + swz];
          acc[nf] = __builtin_amdgcn_mfma_f32_16x16x32_bf16(a, b, acc[nf], 0, 0, 0);
        }
      }
#pragma unroll
      for (int nf = 0; nf < 4; ++nf) {
        int col = h * 64 + nf * 16 + lr;
#pragma unroll
        for (int j = 0; j < 4; ++j) {
          int orow = row0 + w * 16 + g * 4 + j;
          if (orow < M) Cw[(size_t)orow * 128 + col] = f2b(acc[nf][j]);
        }
      }
    }
  }
}

// ---------------- fused dual-edge-type CSR aggregation, 2-way batched gathers:
// einfo[e],einfo[e+1] loaded together; both HSA gathers issued back-to-back
// (halves dependent-load chain depth). Max-combine reorder is bit-identical
// (fmax fully associative/commutative; per-element add unchanged).
__global__ __launch_bounds__(256) void agg2_k(const int* __restrict__ off2,
                                              const int* __restrict__ einfo,
                                              int segbase,
                                              const u16* __restrict__ HSA,
                                              const u16* __restrict__ HSB,
                                              const u16* __restrict__ HD0,
                                              const u16* __restrict__ HD1,
                                              const float* __restrict__ bs0,
                                              const float* __restrict__ bt0,
                                              const float* __restrict__ bs1,
                                              const float* __restrict__ bt1,
                                              const float* __restrict__ esf0,
                                              const float* __restrict__ esf1,
                                              u16* __restrict__ Y, int N) {
  int idx = blockIdx.x * 256 + threadIdx.x;
  int d = idx >> 4;                 // 16 threads per node, 8 features each
  if (d >= N) return;
  int f8 = (idx & 15) << 3;
  int base = (segbase + d) * 2;
  int e0 = off2[base], e1 = off2[base + 1], e2 = off2[base + 2];

  float en[8], es_[8];
#pragma unroll
  for (int k = 0; k < 8; ++k) { en[k] = esf0[f8 + k]; es_[k] = esf0[128 + f8 + k]; }
  float m0[8];
#pragma unroll
  for (int k = 0; k < 8; ++k) m0[k] = -INFINITY;
  int e = e0;
  for (; e + 1 < e1; e += 2) {
    int i0 = einfo[e], i1 = einfo[e + 1];
    int s0 = i0 & 0x7fffffff, s1 = i1 & 0x7fffffff;
    u16x8 h0 = *(const u16x8*)(HSA + (size_t)s0 * 128 + f8);
    u16x8 h1 = *(const u16x8*)(HSA + (size_t)s1 * 128 + f8);
#pragma unroll
    for (int k = 0; k < 8; ++k) {
      float v0 = b2f(h0[k]) + ((i0 < 0) ? es_[k] : en[k]);
      float v1 = b2f(h1[k]) + ((i1 < 0) ? es_[k] : en[k]);
      m0[k] = fmaxf(m0[k], fmaxf(v0, v1));
    }
  }
  if (e < e1) {
    int i0 = einfo[e];
    int s0 = i0 & 0x7fffffff;
    u16x8 h0 = *(const u16x8*)(HSA + (size_t)s0 * 128 + f8);
#pragma unroll
    for (int k = 0; k < 8; ++k)
      m0[k] = fmaxf(m0[k], b2f(h0[k]) + ((i0 < 0) ? es_[k] : en[k]));
  }

#pragma unroll
  for (int k = 0; k < 8; ++k) { en[k] = esf1[f8 + k]; es_[k] = esf1[128 + f8 + k]; }
  float m1[8];
#pragma unroll
  for (int k = 0; k < 8; ++k) m1[k] = -INFINITY;
  e = e1;
  for (; e + 1 < e2; e += 2) {
    int i0 = einfo[e], i1 = einfo[e + 1];
    int s0 = i0 & 0x7fffffff, s1 = i1 & 0x7fffffff;
    u16x8 h0 = *(const u16x8*)(HSB + (size_t)s0 * 128 + f8);
    u16x8 h1 = *(const u16x8*)(HSB + (size_t)s1 * 128 + f8);
#pragma unroll
    for (int k = 0; k < 8; ++k) {
      float v0 = b2f(h0[k]) + ((i0 < 0) ? es_[k] : en[k]);
      float v1 = b2f(h1[k]) + ((i1 < 0) ? es_[k] : en[k]);
      m1[k] = fmaxf(m1[k], fmaxf(v0, v1));
    }
  }
  if (e < e2) {
    int i0 = einfo[e];
    int s0 = i0 & 0x7fffffff;
    u16x8 h0 = *(const u16x8*)(HSB + (size_t)s0 * 128 + f8);
#pragma unroll
    for (int k = 0; k < 8; ++k)
      m1[k] = fmaxf(m1[k], b2f(h0[k]) + ((i0 < 0) ? es_[k] : en[k]));
  }

  u16x8 hd0 = *(const u16x8*)(HD0 + (size_t)d * 128 + f8);
  u16x8 hd1 = *(const u16x8*)(HD1 + (size_t)d * 128 + f8);
  u16x8 o;
#pragma unroll
  for (int k = 0; k < 8; ++k) {
    float r0 = fmaxf(b2f(hd0[k]) + bs0[f8 + k] + bt0[f8 + k] + m0[k], 0.f);
    float r1 = fmaxf(b2f(hd1[k]) + bs1[f8 + k] + bt1[f8 + k] + m1[k], 0.f);
    o[k] = f2b(r0 + r1);
  }
  *(u16x8*)(Y + (size_t)d * 128 + f8) = o;
}

// ---------------- decoder + softmax -> FLOAT32 out: [logits | softmax]
__global__ __launch_bounds__(256) void decoder_k(const u16* __restrict__ X,
                                                 const float* __restrict__ Wd,
                                                 const float* __restrict__ bd,
                                                 float* __restrict__ out) {
  int v = blockIdx.x * 256 + threadIdx.x;
  if (v >= N0) return;
  float a0 = bd[0], a1 = bd[1], a2 = bd[2];
  const u16* x = X + (size_t)v * 128;
#pragma unroll
  for (int k = 0; k < 128; k += 8) {
    u16x8 xv = *(const u16x8*)(x + k);
#pragma unroll
    for (int u = 0; u < 8; ++u) {
      float xf = b2f(xv[u]);
      a0 = fmaf(xf, Wd[k + u], a0);
      a1 = fmaf(xf, Wd[128 + k + u], a1);
      a2 = fmaf(xf, Wd[256 + k + u], a2);
    }
  }
  float mx = fmaxf(a0, fmaxf(a1, a2));
  float e0 = expf(a0 - mx), e1 = expf(a1 - mx), e2 = expf(a2 - mx);
  float inv = 1.f / (e0 + e1 + e2);
  size_t b = (size_t)v * 3;
  out[b + 0] = a0; out[b + 1] = a1; out[b + 2] = a2;
  size_t b2 = (size_t)N0 * 3 + b;
  out[b2 + 0] = e0 * inv; out[b2 + 1] = e1 * inv; out[b2 + 2] = e2 * inv;
}

extern "C" void kernel_launch(void* const* d_in, const int* in_sizes, int n_in,
                              void* d_out, int out_size, void* d_ws, size_t ws_size,
                              hipStream_t stream) {
  float* out = (float*)d_out;

  // ---- sentinel 500: input-size assumption check
  const int expect[15] = {N0, N1, 2 * EE, 2 * EE, 2 * EE, 2 * EE,
                          NAL * 128, 128, 196608, 1536, 196608, 1536,
                          3072, 384, 3};
  bool ok = (n_in == 15);
  if (ok) for (int i = 0; i < 15; ++i) ok = ok && (in_sizes[i] == expect[i]);
  if (!ok) { sentinel_k<<<1, 64, 0, stream>>>(out, 500.f); return; }

  const int* x0_ids = (const int*)d_in[0];
  const int* x1_ids = (const int*)d_in[1];
  const int* es0 = (const int*)d_in[2];
  const int* es1 = (const int*)d_in[3];
  const int* es2 = (const int*)d_in[4];
  const int* es3 = (const int*)d_in[5];
  const float* enc_al   = (const float*)d_in[6];
  const float* emb_test = (const float*)d_in[7];
  const float* W_tgt    = (const float*)d_in[8];
  const float* b_tgt    = (const float*)d_in[9];
  const float* W_src    = (const float*)d_in[10];
  const float* b_src    = (const float*)d_in[11];
  const float* emb_self = (const float*)d_in[12];
  const float* W_dec    = (const float*)d_in[13];
  const float* b_dec    = (const float*)d_in[14];

  // ---- bump allocator (~238 MB < 256 MiB)
  char* base = (char*)d_ws;
  size_t pos = 0;
  auto alloc = [&](size_t bytes) -> void* {
    void* r = base + pos;
    pos += (bytes + 255) & ~(size_t)255;
    return r;
  };
  u16* xs0 = (u16*)alloc((size_t)N0 * 128 * 2);
  u16* xs1 = (u16*)alloc((size_t)N1 * 128 * 2);
  u16* P0  = (u16*)alloc((size_t)N0 * 128 * 2);   // t0 HSA  (Ws_j0 @ xs0)
  u16* P1  = (u16*)alloc((size_t)N0 * 128 * 2);   // HD0
  u16* P2  = (u16*)alloc((size_t)N0 * 128 * 2);   // HD1
  u16* P3  = (u16*)alloc((size_t)N1 * 128 * 2);   // HSB
  u16* P4  = (u16*)alloc((size_t)N0 * 128 * 2);   // t1 HSA  (Ws_j1 @ xs0)
  u16* BP  = (u16*)alloc((size_t)3 * 8 * 16384 * 2);
  int* off2   = (int*)alloc((size_t)(NSEG2 + 1) * 4);
  int* einfo  = (int*)alloc((size_t)TOTE * 4);
  int* counts = (int*)alloc((size_t)NSEG2 * 4);
  int* cursor = counts;                            // reuse: counts dead after scan1
  int* part   = (int*)alloc(1024 * 4);
  if (pos > ws_size) { sentinel_k<<<1, 64, 0, stream>>>(out, 900.f); return; }

  // ---- one-time prep
  prep_w<<<1536, 256, 0, stream>>>(W_src, W_tgt, BP);
  embed2_k<<<((N0 + N1) * 16 + 255) / 256, 256, 0, stream>>>(x0_ids, x1_ids, enc_al, emb_test, xs0, xs1);

  // ---- merged si-split CSR build (once)
  const int EG = (TOTE + 255) / 256;             // 3125
  const int nb = (NSEG2 + 511) / 512;            // 879 <= 1024
  hipMemsetAsync(counts, 0, (size_t)NSEG2 * 4, stream);
  count_all<<<EG, 256, 0, stream>>>(es0, es1, es2, es3, counts);
  scan1_k<<<nb, 512, 0, stream>>>(counts, off2, part, NSEG2);
  scan2_k<<<1, 1024, 0, stream>>>(part, nb);
  scan3_k<<<(NSEG2 + 255) / 256, 256, 0, stream>>>(off2, part, NSEG2, TOTE);
  hipMemsetAsync(cursor, 0, (size_t)NSEG2 * 4, stream);
  fill_all<<<EG, 256, 0, stream>>>(es0, es1, es2, es3, off2, cursor, einfo);

  // ---- layers (agg writes in-place into xs; xs consumed by GEMMs first)
  const int G0 = (N0 + 63) / 64, G1 = (N1 + 63) / 64;
  const int GA0 = (N0 * 16 + 255) / 256, GA1 = (N1 * 16 + 255) / 256;
  for (int i = 0; i < 3; ++i) {
    const u16* BPi = BP + (size_t)i * 8 * 16384;
    // fused: seg0 = xs0 {Ws_j0, Wt_j0, Wt_j2 (,Ws_j1)}; seg1 = xs1 {Ws_j2 -> P3}
    gemm_fused<<<G0 + G1, 256, 0, stream>>>(xs0, N0, G0, BPi + 0 * 16384, (i < 2) ? 4 : 3,
                                            P0, P1, P2, P4,
                                            xs1, N1, BPi + 4 * 16384, P3);
    agg2_k<<<GA0, 256, 0, stream>>>(off2, einfo, 0, P0, P3, P1, P2,
                                    b_src + (size_t)(i * 4 + 0) * 128, b_tgt + (size_t)(i * 4 + 0) * 128,
                                    b_src + (size_t)(i * 4 + 2) * 128, b_tgt + (size_t)(i * 4 + 2) * 128,
                                    emb_self + (size_t)(i * 4 + 0) * 256,
                                    emb_self + (size_t)(i * 4 + 2) * 256, xs0, N0);
    if (i < 2) {
      // xs1 pass: Ws_j3 -> P3, Wt_j1 -> P1, Wt_j3 -> P2 (second segment inert:
      // grid == nB0, so no block enters it)
      gemm_fused<<<G1, 256, 0, stream>>>(xs1, N1, G1, BPi + 5 * 16384, 3,
                                         P3, P1, P2, P2,
                                         xs1, N1, BPi + 4 * 16384, P3);
      agg2_k<<<GA1, 256, 0, stream>>>(off2, einfo, N0, P4, P3, P1, P2,
                                      b_src + (size_t)(i * 4 + 1) * 128, b_tgt + (size_t)(i * 4 + 1) * 128,
                                      b_src + (size_t)(i * 4 + 3) * 128, b_tgt + (size_t)(i * 4 + 3) * 128,
                                      emb_self + (size_t)(i * 4 + 1) * 256,
                                      emb_self + (size_t)(i * 4 + 3) * 256, xs1, N1);
    }
  }

  decoder_k<<<(N0 + 255) / 256, 256, 0, stream>>>(xs0, W_dec, b_dec, out);
}